// Round 8
// baseline (301.617 us; speedup 1.0000x reference)
//
#include <hip/hip_runtime.h>
#include <cstdint>
#include <cstddef>

typedef unsigned short u16;
typedef unsigned int   u32;

typedef __bf16 bf16x8 __attribute__((ext_vector_type(8)));
typedef float  f32x4  __attribute__((ext_vector_type(4)));

#define NROWS 4096
#define INF   512
#define OUTF  512
#define EMB   64
#define MHID  128
#define DB    9
#define KDIM  (INF * DB)   /* 4608 */
#define MN    (NROWS * OUTF)   /* 2097152 */

__device__ __forceinline__ u16 f2bf(float f) {
    union { float f; u32 ui; } v; v.f = f;
    u32 u = v.ui;
    u += 0x7fffu + ((u >> 16) & 1u);   // RTNE
    return (u16)(u >> 16);
}
__device__ __forceinline__ float gridv(int t) { return (float)(t - 3) * 0.4f - 1.0f; }

// ---------------- kernel 1: meff — one wave per output ----------------
__global__ __launch_bounds__(256) void meff_kernel(
    const float* __restrict__ w1_0, const float* __restrict__ b1_0,
    const float* __restrict__ w2_0, const float* __restrict__ b2_0,
    const float* __restrict__ w1_1, const float* __restrict__ b1_1,
    const float* __restrict__ w2_1, const float* __restrict__ b2_1,
    float* __restrict__ Mc)
{
    int tid  = threadIdx.x;
    int lane = tid & 63;
    int wid  = blockIdx.x * 4 + (tid >> 6);
    if (wid >= 1170) return;
    int layer = wid / 585;
    int o     = wid % 585;
    const float* w1 = layer ? w1_1 : w1_0;
    const float* b1 = layer ? b1_1 : b1_0;
    const float* w2 = layer ? w2_1 : w2_0;
    const float* b2 = layer ? b2_1 : b2_0;

    float p;
    int d;
    if (o < 576) {
        int j = o / 9; d = o % 9;
        p = w1[lane * EMB + j]        * w2[d * MHID + lane]
          + w1[(lane + 64) * EMB + j] * w2[d * MHID + lane + 64];
    } else {
        d = o - 576;
        p = b1[lane] * w2[d * MHID + lane] + b1[lane + 64] * w2[d * MHID + lane + 64];
    }
#pragma unroll
    for (int off = 32; off >= 1; off >>= 1)
        p += __shfl_xor(p, off, 64);
    if (lane == 0) {
        if (o >= 576) p += b2[d];
        Mc[layer * 1024 + o] = p;
    }
}

// ---------------- kernel 2: genw v9b — v9 + VGPR-cap fix ----------
// R9 post-mortem: v9's prefetch array SPILLED to scratch — WRITE_SIZE
// 9.2->136.5 MB (output is 9.4 MB!), FETCH +28 MB, VGPR_Count stuck at 52:
// default occupancy heuristic capped VGPRs at <=64 (8 waves/SIMD target)
// and the 32-VGPR vreg[8] went to scratch; ~200 MB round-trip ~= the
// 28 us regression. Fix: __launch_bounds__(256, 4) -> 4 waves/EU min
// (= the 40-KB-LDS cap anyway), VGPR ceiling 128, no spill. Pipeline
// structure unchanged (T14 issue-early/write-late, persistent 4 chunks).
__global__ __launch_bounds__(256, 4) void genw_kernel(
    const float* __restrict__ emb0, const float* __restrict__ emb1,
    const float* __restrict__ Mc,
    u16* __restrict__ Bw0, u16* __restrict__ Bw1)
{
    __shared__ __align__(16) float4 tile[128 * 16];   // 32768 B, c4-XOR swizzle
    __shared__ __align__(16) float  pbuf[128 * 9];    //  4608 B partials (stride 9, odd)
    __shared__ __align__(16) u16    ob[128 * 9];      //  2304 B out-stage
    int layer = blockIdx.y;
    const float* emb = layer ? emb1 : emb0;
    u16* Bw = layer ? Bw1 : Bw0;
    const float* mc = Mc + layer * 1024;

    int tid = threadIdx.x;
    int r   = tid & 127;                     // owned row
    int hi  = tid >> 7;                      // 0: cols 0-31, 1: cols 32-63 (wave-uniform)
    int cb  = hi * 8;                        // float4 base in tile
    // SGPR base so mc[] offsets are compile-time constants -> s_load
    const float* mcp = mc + __builtin_amdgcn_readfirstlane(hi) * 32 * 9;

    const int CH = 4;                        // chunks per block, stride gridDim.x
    float4 vreg[8];

    // prologue: stage chunk 0
    {
        size_t rowbase = (size_t)blockIdx.x * 128;
        const float4* g4 = (const float4*)(emb + rowbase * EMB);
#pragma unroll
        for (int q = 0; q < 8; ++q) vreg[q] = g4[q * 256 + tid];
#pragma unroll
        for (int q = 0; q < 8; ++q) {
            int f = q * 256 + tid;
            int row = f >> 4, c4 = f & 15;
            tile[row * 16 + (c4 ^ (row & 15))] = vreg[q];
        }
    }
    __syncthreads();

    for (int ch = 0; ch < CH; ++ch) {
        size_t rowbase = (size_t)(ch * 512 + blockIdx.x) * 128;

        // T14 issue-early: next chunk's loads in flight under this chunk's compute
        if (ch + 1 < CH) {
            size_t nb = (size_t)((ch + 1) * 512 + blockIdx.x) * 128;
            const float4* g4 = (const float4*)(emb + nb * EMB);
#pragma unroll
            for (int q = 0; q < 8; ++q) vreg[q] = g4[q * 256 + tid];
        }

        float acc[9];
#pragma unroll
        for (int d = 0; d < 9; ++d) acc[d] = hi ? 0.0f : mc[576 + d];

#pragma unroll
        for (int jj = 0; jj < 8; ++jj) {
            float4 v = tile[r * 16 + ((cb + jj) ^ (r & 15))];
#pragma unroll
            for (int d = 0; d < 9; ++d)
                acc[d] += v.x * mcp[(jj * 4 + 0) * 9 + d]
                        + v.y * mcp[(jj * 4 + 1) * 9 + d]
                        + v.z * mcp[(jj * 4 + 2) * 9 + d]
                        + v.w * mcp[(jj * 4 + 3) * 9 + d];
        }

        if (hi) {
#pragma unroll
            for (int d = 0; d < 9; ++d) pbuf[r * 9 + d] = acc[d];
        }
        __syncthreads();                     // b1: all tile reads + pbuf done

        // write-late: refill tile (drained at b1) while lo-threads combine
        if (ch + 1 < CH) {
#pragma unroll
            for (int q = 0; q < 8; ++q) {
                int f = q * 256 + tid;
                int row = f >> 4, c4 = f & 15;
                tile[row * 16 + (c4 ^ (row & 15))] = vreg[q];
            }
        }
        if (!hi) {
#pragma unroll
            for (int d = 0; d < 9; ++d) ob[r * 9 + d] = f2bf(acc[d] + pbuf[r * 9 + d]);
        }
        __syncthreads();                     // b2: ob + new tile visible

        const uint4* src = (const uint4*)ob;               // 144 uint4
        uint4* dst = (uint4*)(Bw + rowbase * 9);           // 2304 B/chunk, aligned
        if (tid < 144) dst[tid] = src[tid];
        __syncthreads();                     // b3: ob consumed before next combine
    }
}

// ---------------- kernel 3: phi — div-free spline + silu ----------------
__global__ __launch_bounds__(256) void phi_kernel(const float* __restrict__ xin,
                                                  const float* __restrict__ part,
                                                  int S,
                                                  u16* __restrict__ phi)
{
    __shared__ __align__(16) u16 lbuf[256 * 9];   // 4608 B
    int tid = threadIdx.x;
    int idx = blockIdx.x * 256 + tid;

    float xv;
    if (part) {
        xv = 0.f;
        for (int z = 0; z < S; ++z) xv += part[(size_t)z * MN + idx];
    } else {
        xv = xin[idx];
    }

    float b[11];
#pragma unroll
    for (int t = 0; t < 11; ++t)
        b[t] = (xv >= gridv(t) && xv < gridv(t + 1)) ? 1.0f : 0.0f;
#pragma unroll
    for (int k = 1; k <= 3; ++k) {
#pragma unroll
        for (int t = 0; t + k < 11; ++t) {
            float rdp = 1.0f / ((gridv(t + k) - gridv(t)) + 1e-8f);
            float rdn = 1.0f / ((gridv(t + k + 1) - gridv(t + 1)) + 1e-8f);
            b[t] = (xv - gridv(t)) * rdp * b[t] + (gridv(t + k + 1) - xv) * rdn * b[t + 1];
        }
    }
    float sil = xv / (1.0f + expf(-xv));

#pragma unroll
    for (int d = 0; d < 8; ++d) lbuf[tid * 9 + d] = f2bf(b[d]);
    lbuf[tid * 9 + 8] = f2bf(sil);
    __syncthreads();

    const uint4* src = (const uint4*)lbuf;        // 288 uint4
    uint4* dst = (uint4*)(phi + (size_t)blockIdx.x * 256 * 9);
    for (int s = tid; s < 288; s += 256) dst[s] = src[s];
}

// ---------------- kernel 4: split-K GEMM  Cpart[z] = A[:,kz] * B[:,kz]^T ----------
#define GLOAD16(gp, lp) __builtin_amdgcn_global_load_lds(                         \
    (const __attribute__((address_space(1))) u32*)(gp),                           \
    (__attribute__((address_space(3))) u32*)(lp), 16, 0, 0)

__global__ __launch_bounds__(256, 4) void gemm_kernel(const __bf16* __restrict__ A,
                                                      const __bf16* __restrict__ B,
                                                      float* __restrict__ Cpart,
                                                      int N, int K, int ksz)
{
    __shared__ __align__(16) __bf16 As[128 * 64];
    __shared__ __align__(16) __bf16 Bs[128 * 64];

    int tid  = threadIdx.x;
    int lane = tid & 63;
    int wv   = tid >> 6;
    int wm   = wv >> 1, wn = wv & 1;
    int brow = blockIdx.x * 128;
    int bcol = blockIdx.y * 128;
    int z    = blockIdx.z;
    int kbeg = z * ksz, kend = kbeg + ksz;

    f32x4 acc[4][4];
#pragma unroll
    for (int r = 0; r < 4; ++r)
#pragma unroll
        for (int c = 0; c < 4; ++c)
#pragma unroll
            for (int g = 0; g < 4; ++g) acc[r][c][g] = 0.0f;

    int quad = lane >> 4;
    int l16  = lane & 15;

    for (int k0 = kbeg; k0 < kend; k0 += 64) {
#pragma unroll
        for (int q = 0; q < 4; ++q) {
            int chunk = q * 256 + wv * 64 + lane;
            int row   = chunk >> 3;
            int slot  = chunk & 7;
            int col   = ((slot ^ (row & 7)) << 3);   // XOR swizzle (0 conflicts, R2)
            const __bf16* ga = A + (size_t)(brow + row) * K + (k0 + col);
            const __bf16* gb = B + (size_t)(bcol + row) * K + (k0 + col);
            GLOAD16(ga, &As[(q * 256 + wv * 64) * 8]);
            GLOAD16(gb, &Bs[(q * 256 + wv * 64) * 8]);
        }
        __syncthreads();

#pragma unroll
        for (int ks = 0; ks < 2; ++ks) {
            bf16x8 af[4], bfr[4];
#pragma unroll
            for (int r = 0; r < 4; ++r) {
                int arow = wm * 64 + r * 16 + l16;
                af[r] = *(const bf16x8*)&As[arow * 64 + (((ks * 4 + quad) ^ (arow & 7)) << 3)];
                int brw = wn * 64 + r * 16 + l16;
                bfr[r] = *(const bf16x8*)&Bs[brw * 64 + (((ks * 4 + quad) ^ (brw & 7)) << 3)];
            }
#pragma unroll
            for (int r = 0; r < 4; ++r)
#pragma unroll
                for (int c = 0; c < 4; ++c)
                    acc[r][c] = __builtin_amdgcn_mfma_f32_16x16x32_bf16(af[r], bfr[c], acc[r][c], 0, 0, 0);
        }
        __syncthreads();
    }

    float* Cz = Cpart + (size_t)z * MN;
#pragma unroll
    for (int r = 0; r < 4; ++r)
#pragma unroll
        for (int c = 0; c < 4; ++c)
#pragma unroll
            for (int g = 0; g < 4; ++g) {
                int grow = brow + wm * 64 + r * 16 + quad * 4 + g;
                int gcol = bcol + wn * 64 + c * 16 + l16;
                Cz[(size_t)grow * N + gcol] = acc[r][c][g];
            }
}

// ---------------- kernel 5: final reduce (float4) ----------------
__global__ __launch_bounds__(256) void reduce_kernel(const float* __restrict__ part,
                                                     int S, float* __restrict__ out)
{
    int i = blockIdx.x * 256 + threadIdx.x;
    const float4* p4 = (const float4*)part;
    float4 s = p4[i];
    for (int z = 1; z < S; ++z) {
        float4 v = p4[(size_t)z * (MN / 4) + i];
        s.x += v.x; s.y += v.y; s.z += v.z; s.w += v.w;
    }
    ((float4*)out)[i] = s;
}

// ---------------- launch ----------------
extern "C" void kernel_launch(void* const* d_in, const int* in_sizes, int n_in,
                              void* d_out, int out_size, void* d_ws, size_t ws_size,
                              hipStream_t stream)
{
    const float* x    = (const float*)d_in[0];
    const float* emb0 = (const float*)d_in[1];
    const float* w1_0 = (const float*)d_in[2];
    const float* b1_0 = (const float*)d_in[3];
    const float* w2_0 = (const float*)d_in[4];
    const float* b2_0 = (const float*)d_in[5];
    const float* emb1 = (const float*)d_in[6];
    const float* w1_1 = (const float*)d_in[7];
    const float* b1_1 = (const float*)d_in[8];
    const float* w2_1 = (const float*)d_in[9];
    const float* b2_1 = (const float*)d_in[10];

    char* ws = (char*)d_ws;
    const size_t PHI_OFF  = 0;                       // 37,748,736
    const size_t BW0_OFF  = 37748736;                //  4,718,592
    const size_t BW1_OFF  = BW0_OFF + 4718592;
    const size_t MC_OFF   = BW1_OFF + 4718592;       //  8,192
    const size_t PART_OFF = MC_OFF + 8192;

    // split-K: S=4 (R3 vs R4 A/B: S=8 cost ~+19 us in partial traffic)
    int S = 1;
    const size_t SLAB = 8388608ull;
    if      (ws_size >= PART_OFF + 4 * SLAB) S = 4;
    else if (ws_size >= PART_OFF + 2 * SLAB) S = 2;
    int ksz = KDIM / S;

    u16*   phi  = (u16*)(ws + PHI_OFF);
    u16*   Bw0  = (u16*)(ws + BW0_OFF);
    u16*   Bw1  = (u16*)(ws + BW1_OFF);
    float* Mc   = (float*)(ws + MC_OFF);
    float* part = (float*)(ws + PART_OFF);

    meff_kernel<<<293, 256, 0, stream>>>(w1_0, b1_0, w2_0, b2_0,
                                         w1_1, b1_1, w2_1, b2_1, Mc);
    genw_kernel<<<dim3(512, 2), 256, 0, stream>>>(emb0, emb1, Mc, Bw0, Bw1);

    phi_kernel<<<8192, 256, 0, stream>>>(x, nullptr, 0, phi);
    gemm_kernel<<<dim3(32, 4, S), 256, 0, stream>>>((const __bf16*)phi, (const __bf16*)Bw0,
                                                    part, OUTF, KDIM, ksz);
    phi_kernel<<<8192, 256, 0, stream>>>(nullptr, part, S, phi);
    gemm_kernel<<<dim3(32, 4, S), 256, 0, stream>>>((const __bf16*)phi, (const __bf16*)Bw1,
                                                    part, OUTF, KDIM, ksz);
    reduce_kernel<<<2048, 256, 0, stream>>>(part, S, (float*)d_out);
}

// Round 9
// 267.496 us; speedup vs baseline: 1.1276x; 1.1276x over previous
//
#include <hip/hip_runtime.h>
#include <cstdint>
#include <cstddef>

typedef unsigned short u16;
typedef unsigned int   u32;

typedef __bf16 bf16x8 __attribute__((ext_vector_type(8)));
typedef float  f32x4  __attribute__((ext_vector_type(4)));

#define NROWS 4096
#define INF   512
#define OUTF  512
#define EMB   64
#define MHID  128
#define DB    9
#define KDIM  (INF * DB)   /* 4608 */
#define MN    (NROWS * OUTF)   /* 2097152 */

__device__ __forceinline__ u16 f2bf(float f) {
    union { float f; u32 ui; } v; v.f = f;
    u32 u = v.ui;
    u += 0x7fffu + ((u >> 16) & 1u);   // RTNE
    return (u16)(u >> 16);
}
__device__ __forceinline__ float gridv(int t) { return (float)(t - 3) * 0.4f - 1.0f; }

#define GLOAD16(gp, lp) __builtin_amdgcn_global_load_lds(                         \
    (const __attribute__((address_space(1))) u32*)(gp),                           \
    (__attribute__((address_space(3))) u32*)(lp), 16, 0, 0)

// ---------------- kernel 1: meff — one wave per output ----------------
__global__ __launch_bounds__(256) void meff_kernel(
    const float* __restrict__ w1_0, const float* __restrict__ b1_0,
    const float* __restrict__ w2_0, const float* __restrict__ b2_0,
    const float* __restrict__ w1_1, const float* __restrict__ b1_1,
    const float* __restrict__ w2_1, const float* __restrict__ b2_1,
    float* __restrict__ Mc)
{
    int tid  = threadIdx.x;
    int lane = tid & 63;
    int wid  = blockIdx.x * 4 + (tid >> 6);
    if (wid >= 1170) return;
    int layer = wid / 585;
    int o     = wid % 585;
    const float* w1 = layer ? w1_1 : w1_0;
    const float* b1 = layer ? b1_1 : b1_0;
    const float* w2 = layer ? w2_1 : w2_0;
    const float* b2 = layer ? b2_1 : b2_0;

    float p;
    int d;
    if (o < 576) {
        int j = o / 9; d = o % 9;
        p = w1[lane * EMB + j]        * w2[d * MHID + lane]
          + w1[(lane + 64) * EMB + j] * w2[d * MHID + lane + 64];
    } else {
        d = o - 576;
        p = b1[lane] * w2[d * MHID + lane] + b1[lane + 64] * w2[d * MHID + lane + 64];
    }
#pragma unroll
    for (int off = 32; off >= 1; off >>= 1)
        p += __shfl_xor(p, off, 64);
    if (lane == 0) {
        if (o >= 576) p += b2[d];
        Mc[layer * 1024 + o] = p;
    }
}

// ---------------- kernel 2: genw v10 — gload_lds double-buffer (T3 2-phase) --
// R10 post-mortem: launch_bounds(256,4) did NOT lift the 52-VGPR alloc;
// vreg[] spill persisted (WRITE 140 MB). v10 removes VGPR staging entirely:
// global_load_lds width=16 into a double-buffered 2x32KB tile. Per chunk:
// issue next chunk's 32 gload_lds (async, vmcnt) -> compute current buffer
// -> syncthreads (vmcnt drain = next buffer ready). Loads in flight under
// the whole compute phase (T3 minimum 2-phase, m97 pattern). XOR swizzle
// moved to the GLOBAL source address (linear LDS dest + inv-swz source +
// swz read, rule #21); read path identical to v8 (~0 conflicts). Persistent
// 256x2 grid, CH=8, 2 barriers/chunk.
__global__ __launch_bounds__(256, 2) void genw_kernel(
    const float* __restrict__ emb0, const float* __restrict__ emb1,
    const float* __restrict__ Mc,
    u16* __restrict__ Bw0, u16* __restrict__ Bw1)
{
    __shared__ __align__(16) float4 tile[2][128 * 16]; // 65536 B, swz on read
    __shared__ __align__(16) float  pbuf[128 * 9];     //  4608 B (stride 9, odd)
    __shared__ __align__(16) u16    ob[128 * 9];       //  2304 B out-stage
    int layer = blockIdx.y;
    const float* emb = layer ? emb1 : emb0;
    u16* Bw = layer ? Bw1 : Bw0;
    const float* mc = Mc + layer * 1024;

    int tid = threadIdx.x;
    int wb  = tid & ~63;                     // wave-uniform lane-block base
    int r   = tid & 127;                     // owned row
    int hi  = tid >> 7;                      // 0: cols 0-31, 1: cols 32-63 (wave-uniform)
    int cb  = hi * 8;                        // float4 base in tile
    // SGPR base so mc[] offsets are compile-time constants -> s_load
    const float* mcp = mc + __builtin_amdgcn_readfirstlane(hi) * 32 * 9;

    const int CH = 8;                        // chunks per block, stride 256

    // stage chunk ch into buffer b: LDS slot f=q*256+tid holds emb float4
    // (row=f>>4, col=(f&15)^(row&15)) -> read with same XOR is conflict-clean
#define STAGE_GL(b, ch)                                                        \
    {                                                                          \
        const float4* g4 = (const float4*)(emb + (size_t)((ch) * 256 + blockIdx.x) * 128 * EMB); \
        _Pragma("unroll")                                                      \
        for (int q = 0; q < 8; ++q) {                                          \
            int f   = q * 256 + tid;                                           \
            int row = f >> 4, c4s = f & 15;                                    \
            GLOAD16(g4 + row * 16 + (c4s ^ (row & 15)), &tile[b][q * 256 + wb]); \
        }                                                                      \
    }

    STAGE_GL(0, 0);
    __syncthreads();                         // prologue drain: buf0 ready

    int cur = 0;
    for (int ch = 0; ch < CH; ++ch) {
        size_t rowbase = (size_t)(ch * 256 + blockIdx.x) * 128;

        if (ch + 1 < CH) STAGE_GL(cur ^ 1, ch + 1);   // async, rides under compute

        float acc[9];
#pragma unroll
        for (int d = 0; d < 9; ++d) acc[d] = hi ? 0.0f : mc[576 + d];

#pragma unroll
        for (int jj = 0; jj < 8; ++jj) {
            float4 v = tile[cur][r * 16 + ((cb + jj) ^ (r & 15))];
#pragma unroll
            for (int d = 0; d < 9; ++d)
                acc[d] += v.x * mcp[(jj * 4 + 0) * 9 + d]
                        + v.y * mcp[(jj * 4 + 1) * 9 + d]
                        + v.z * mcp[(jj * 4 + 2) * 9 + d]
                        + v.w * mcp[(jj * 4 + 3) * 9 + d];
        }

        if (hi) {
#pragma unroll
            for (int d = 0; d < 9; ++d) pbuf[r * 9 + d] = acc[d];
        }
        __syncthreads();                     // b1: tile reads + pbuf done; vmcnt
                                             //     drain -> next buffer landed
        if (!hi) {
#pragma unroll
            for (int d = 0; d < 9; ++d) ob[r * 9 + d] = f2bf(acc[d] + pbuf[r * 9 + d]);
        }
        __syncthreads();                     // b2: ob visible

        const uint4* src = (const uint4*)ob;               // 144 uint4
        uint4* dst = (uint4*)(Bw + rowbase * 9);           // 2304 B/chunk, aligned
        if (tid < 144) dst[tid] = src[tid];
        // no b3 needed: next ob write is after next b1; flush ds_reads are
        // lgkm-drained there; pbuf(n+1) writes are post-b2(n).
        cur ^= 1;
    }
#undef STAGE_GL
}

// ---------------- kernel 3: phi — div-free spline + silu ----------------
__global__ __launch_bounds__(256) void phi_kernel(const float* __restrict__ xin,
                                                  const float* __restrict__ part,
                                                  int S,
                                                  u16* __restrict__ phi)
{
    __shared__ __align__(16) u16 lbuf[256 * 9];   // 4608 B
    int tid = threadIdx.x;
    int idx = blockIdx.x * 256 + tid;

    float xv;
    if (part) {
        xv = 0.f;
        for (int z = 0; z < S; ++z) xv += part[(size_t)z * MN + idx];
    } else {
        xv = xin[idx];
    }

    float b[11];
#pragma unroll
    for (int t = 0; t < 11; ++t)
        b[t] = (xv >= gridv(t) && xv < gridv(t + 1)) ? 1.0f : 0.0f;
#pragma unroll
    for (int k = 1; k <= 3; ++k) {
#pragma unroll
        for (int t = 0; t + k < 11; ++t) {
            float rdp = 1.0f / ((gridv(t + k) - gridv(t)) + 1e-8f);
            float rdn = 1.0f / ((gridv(t + k + 1) - gridv(t + 1)) + 1e-8f);
            b[t] = (xv - gridv(t)) * rdp * b[t] + (gridv(t + k + 1) - xv) * rdn * b[t + 1];
        }
    }
    float sil = xv / (1.0f + expf(-xv));

#pragma unroll
    for (int d = 0; d < 8; ++d) lbuf[tid * 9 + d] = f2bf(b[d]);
    lbuf[tid * 9 + 8] = f2bf(sil);
    __syncthreads();

    const uint4* src = (const uint4*)lbuf;        // 288 uint4
    uint4* dst = (uint4*)(phi + (size_t)blockIdx.x * 256 * 9);
    for (int s = tid; s < 288; s += 256) dst[s] = src[s];
}

// ---------------- kernel 4: split-K GEMM  Cpart[z] = A[:,kz] * B[:,kz]^T ----------
__global__ __launch_bounds__(256, 4) void gemm_kernel(const __bf16* __restrict__ A,
                                                      const __bf16* __restrict__ B,
                                                      float* __restrict__ Cpart,
                                                      int N, int K, int ksz)
{
    __shared__ __align__(16) __bf16 As[128 * 64];
    __shared__ __align__(16) __bf16 Bs[128 * 64];

    int tid  = threadIdx.x;
    int lane = tid & 63;
    int wv   = tid >> 6;
    int wm   = wv >> 1, wn = wv & 1;
    int brow = blockIdx.x * 128;
    int bcol = blockIdx.y * 128;
    int z    = blockIdx.z;
    int kbeg = z * ksz, kend = kbeg + ksz;

    f32x4 acc[4][4];
#pragma unroll
    for (int r = 0; r < 4; ++r)
#pragma unroll
        for (int c = 0; c < 4; ++c)
#pragma unroll
            for (int g = 0; g < 4; ++g) acc[r][c][g] = 0.0f;

    int quad = lane >> 4;
    int l16  = lane & 15;

    for (int k0 = kbeg; k0 < kend; k0 += 64) {
#pragma unroll
        for (int q = 0; q < 4; ++q) {
            int chunk = q * 256 + wv * 64 + lane;
            int row   = chunk >> 3;
            int slot  = chunk & 7;
            int col   = ((slot ^ (row & 7)) << 3);   // XOR swizzle (0 conflicts, R2)
            const __bf16* ga = A + (size_t)(brow + row) * K + (k0 + col);
            const __bf16* gb = B + (size_t)(bcol + row) * K + (k0 + col);
            GLOAD16(ga, &As[(q * 256 + wv * 64) * 8]);
            GLOAD16(gb, &Bs[(q * 256 + wv * 64) * 8]);
        }
        __syncthreads();

#pragma unroll
        for (int ks = 0; ks < 2; ++ks) {
            bf16x8 af[4], bfr[4];
#pragma unroll
            for (int r = 0; r < 4; ++r) {
                int arow = wm * 64 + r * 16 + l16;
                af[r] = *(const bf16x8*)&As[arow * 64 + (((ks * 4 + quad) ^ (arow & 7)) << 3)];
                int brw = wn * 64 + r * 16 + l16;
                bfr[r] = *(const bf16x8*)&Bs[brw * 64 + (((ks * 4 + quad) ^ (brw & 7)) << 3)];
            }
#pragma unroll
            for (int r = 0; r < 4; ++r)
#pragma unroll
                for (int c = 0; c < 4; ++c)
                    acc[r][c] = __builtin_amdgcn_mfma_f32_16x16x32_bf16(af[r], bfr[c], acc[r][c], 0, 0, 0);
        }
        __syncthreads();
    }

    float* Cz = Cpart + (size_t)z * MN;
#pragma unroll
    for (int r = 0; r < 4; ++r)
#pragma unroll
        for (int c = 0; c < 4; ++c)
#pragma unroll
            for (int g = 0; g < 4; ++g) {
                int grow = brow + wm * 64 + r * 16 + quad * 4 + g;
                int gcol = bcol + wn * 64 + c * 16 + l16;
                Cz[(size_t)grow * N + gcol] = acc[r][c][g];
            }
}

// ---------------- kernel 5: final reduce (float4) ----------------
__global__ __launch_bounds__(256) void reduce_kernel(const float* __restrict__ part,
                                                     int S, float* __restrict__ out)
{
    int i = blockIdx.x * 256 + threadIdx.x;
    const float4* p4 = (const float4*)part;
    float4 s = p4[i];
    for (int z = 1; z < S; ++z) {
        float4 v = p4[(size_t)z * (MN / 4) + i];
        s.x += v.x; s.y += v.y; s.z += v.z; s.w += v.w;
    }
    ((float4*)out)[i] = s;
}

// ---------------- launch ----------------
extern "C" void kernel_launch(void* const* d_in, const int* in_sizes, int n_in,
                              void* d_out, int out_size, void* d_ws, size_t ws_size,
                              hipStream_t stream)
{
    const float* x    = (const float*)d_in[0];
    const float* emb0 = (const float*)d_in[1];
    const float* w1_0 = (const float*)d_in[2];
    const float* b1_0 = (const float*)d_in[3];
    const float* w2_0 = (const float*)d_in[4];
    const float* b2_0 = (const float*)d_in[5];
    const float* emb1 = (const float*)d_in[6];
    const float* w1_1 = (const float*)d_in[7];
    const float* b1_1 = (const float*)d_in[8];
    const float* w2_1 = (const float*)d_in[9];
    const float* b2_1 = (const float*)d_in[10];

    char* ws = (char*)d_ws;
    const size_t PHI_OFF  = 0;                       // 37,748,736
    const size_t BW0_OFF  = 37748736;                //  4,718,592
    const size_t BW1_OFF  = BW0_OFF + 4718592;
    const size_t MC_OFF   = BW1_OFF + 4718592;       //  8,192
    const size_t PART_OFF = MC_OFF + 8192;

    // split-K: S=4 (R3 vs R4 A/B: S=8 cost ~+19 us in partial traffic)
    int S = 1;
    const size_t SLAB = 8388608ull;
    if      (ws_size >= PART_OFF + 4 * SLAB) S = 4;
    else if (ws_size >= PART_OFF + 2 * SLAB) S = 2;
    int ksz = KDIM / S;

    u16*   phi  = (u16*)(ws + PHI_OFF);
    u16*   Bw0  = (u16*)(ws + BW0_OFF);
    u16*   Bw1  = (u16*)(ws + BW1_OFF);
    float* Mc   = (float*)(ws + MC_OFF);
    float* part = (float*)(ws + PART_OFF);

    meff_kernel<<<293, 256, 0, stream>>>(w1_0, b1_0, w2_0, b2_0,
                                         w1_1, b1_1, w2_1, b2_1, Mc);
    genw_kernel<<<dim3(256, 2), 256, 0, stream>>>(emb0, emb1, Mc, Bw0, Bw1);

    phi_kernel<<<8192, 256, 0, stream>>>(x, nullptr, 0, phi);
    gemm_kernel<<<dim3(32, 4, S), 256, 0, stream>>>((const __bf16*)phi, (const __bf16*)Bw0,
                                                    part, OUTF, KDIM, ksz);
    phi_kernel<<<8192, 256, 0, stream>>>(nullptr, part, S, phi);
    gemm_kernel<<<dim3(32, 4, S), 256, 0, stream>>>((const __bf16*)phi, (const __bf16*)Bw1,
                                                    part, OUTF, KDIM, ksz);
    reduce_kernel<<<2048, 256, 0, stream>>>(part, S, (float*)d_out);
}